// Round 11
// baseline (35.166 us; speedup 1.0000x reference)
//
#include <hip/hip_runtime.h>

// MultiHeadRouter: B=2, L=4096, H=16, S=64, D=128
// out (float32): [T*H ones][T*H argmax-as-float][1 loss], T = 8192
//
// R11 = R10 (bi-major, A-direct-VGPR, B fragment planes in LDS) +
//   persistent blocks: grid 512, each wave walks 4 sequential 16-token tiles,
//   B staged ONCE per block (4x amortization), and tile it+1's A-loads issued
//   before computing tile it (register prefetch: HBM latency hides under
//   split+MFMA+epilogue instead of being barrier-drained per block).
// LDS dead-padded to 48 KB: 3 blocks/CU -> allocator VGPR budget ~170 >=
//   demand ~130 (the session's proven allocator lever: budget follows LDS).
// f16 2-split MFMA chain + epilogue bit-identical to R4-R10 (absmax 0 x7).

#define TOKENS  8192
#define NHEAD   16
#define NSTATE  64
#define DDIM    128
#define TH      (TOKENS * NHEAD)
#define WFRAG_BYTES (1u << 19)   // 512 KB: 16 heads x 32 KB fragment planes

typedef _Float16 half8 __attribute__((ext_vector_type(8)));
typedef float    f32x4 __attribute__((ext_vector_type(4)));

constexpr int TPW   = 16;                    // tokens per wave-tile (one m-tile)
constexpr int WAVES = 4;
constexpr int ITERS = 4;                     // tiles per wave
constexpr int NBLK  = 512;                   // h = blk&15, window = blk>>4 (32)

#define GLOAD_LDS16(gsrc, ldst)                                           \
    __builtin_amdgcn_global_load_lds(                                     \
        (const __attribute__((address_space(1))) void*)(gsrc),            \
        (__attribute__((address_space(3))) void*)(ldst), 16, 0, 0)

__device__ __forceinline__ unsigned int ordf(float f) {
    unsigned int u = __float_as_uint(f);
    return (u & 0x80000000u) ? ~u : (u | 0x80000000u);   // order-preserving
}

// RNE f32 -> (f16 hi, f16 lo) split of 8 floats (two f32x4)
__device__ __forceinline__ void split8(const f32x4 v0, const f32x4 v1,
                                       half8& hh, half8& ll) {
    #pragma unroll
    for (int j = 0; j < 4; ++j) {
        _Float16 h0 = (_Float16)v0[j];
        hh[j]     = h0;  ll[j]     = (_Float16)(v0[j] - (float)h0);
        _Float16 h1 = (_Float16)v1[j];
        hh[4 + j] = h1;  ll[4 + j] = (_Float16)(v1[j] - (float)h1);
    }
}

// One-shot: w[H,S,D] fp32 -> fragment-ordered f16 hi/lo planes (R7-verified).
__global__ __launch_bounds__(256)
void prep_w(const float* __restrict__ w, half8* __restrict__ wfrag)
{
    const int t    = blockIdx.x * 256 + threadIdx.x;   // 16384 threads
    const int lane = t & 63;
    const int n    = (t >> 6) & 3;
    const int ks   = (t >> 8) & 3;
    const int h    = t >> 10;
    const int s    = n * 16 + (lane & 15);
    const int k0   = ks * 32 + (lane >> 4) * 8;
    const float* src = w + (size_t)(h * NSTATE + s) * DDIM + k0;
    f32x4 v0 = *reinterpret_cast<const f32x4*>(src);
    f32x4 v1 = *reinterpret_cast<const f32x4*>(src + 4);
    half8 hv, lv;
    split8(v0, v1, hv, lv);
    const size_t hb = (size_t)h * 2048;                // 2048 half8 per head
    const int fb = (ks * 4 + n) * 2;
    wfrag[hb + (size_t)fb * 64 + lane]       = hv;
    wfrag[hb + (size_t)(fb + 1) * 64 + lane] = lv;
}

__global__ __launch_bounds__(256)
void router_mfma(const float* __restrict__ x,      // [T,H,D]
                 const half8* __restrict__ wfrag,  // fragment planes (prep_w)
                 const float* __restrict__ bias,   // [H,S]
                 float* __restrict__ out,
                 float* __restrict__ ws_sums,      // [H,S]
                 int*   __restrict__ ws_cnts)      // [H,S]
{
    // [0,32K): B fragment planes. [32K,48K): dead pad — occupancy control:
    // 48 KB -> 3 blocks/CU -> allocator VGPR budget ~170 (no spill at ~130).
    // First 2 KB reused for the final block reduction.
    __shared__ __align__(16) unsigned char smem[49152];

    const int blk  = blockIdx.x;
    const int h    = blk & 15;          // bi-major: concurrent blocks span heads
    const int w0   = blk >> 4;          // token window [w0*256, w0*256+256)
    const int tid  = threadIdx.x;
    const int wave = __builtin_amdgcn_readfirstlane(tid >> 6);
    const int lane = tid & 63;
    const int col  = lane & 15;         // A-row (token low) == B-state low bits
    const int kg   = lane >> 4;
    const int base = w0 * 256 + wave * TPW;   // this wave's first token

    const size_t srow = (size_t)(NHEAD * DDIM);
    const float* arow0 = x + (size_t)(base + col) * srow + h * DDIM + kg * 8;

    // ---- issue tile 0's A loads first (longest latency) ----
    f32x4 gA[4][2], gB[4][2];
    #pragma unroll
    for (int ks = 0; ks < 4; ++ks) {
        gA[ks][0] = *reinterpret_cast<const f32x4*>(arow0 + ks * 32);
        gA[ks][1] = *reinterpret_cast<const f32x4*>(arow0 + ks * 32 + 4);
    }

    // ---- stage B once: 32 KB linear copy of this head's planes (L2-hot) ----
    {
        const char* wsrc = (const char*)wfrag + (size_t)h * 32768;
        #pragma unroll
        for (int i = 0; i < 8; ++i) {
            const int off = (wave * 8 + i) * 1024;
            GLOAD_LDS16(wsrc + off + lane * 16, smem + off);
        }
    }

    const float b0 = bias[h * NSTATE +  0 + col];
    const float b1 = bias[h * NSTATE + 16 + col];
    const float b2 = bias[h * NSTATE + 32 + col];
    const float b3 = bias[h * NSTATE + 48 + col];

    __syncthreads();   // drains tile-0 A + B; the only staging barrier

    float sc[4] = {0.f, 0.f, 0.f, 0.f};
    int   cn[4] = {0, 0, 0, 0};

    #pragma unroll
    for (int it = 0; it < ITERS; ++it) {      // compile-time it (rule 20)
        f32x4 (&gc)[4][2] = (it & 1) ? gB : gA;   // static after unroll
        f32x4 (&gn)[4][2] = (it & 1) ? gA : gB;

        // prefetch tile it+1: loads fly under this tile's compute
        if (it < ITERS - 1) {
            const float* arow = arow0 + (size_t)(it + 1) * 64 * srow;
            #pragma unroll
            for (int ks = 0; ks < 4; ++ks) {
                gn[ks][0] = *reinterpret_cast<const f32x4*>(arow + ks * 32);
                gn[ks][1] = *reinterpret_cast<const f32x4*>(arow + ks * 32 + 4);
            }
        }

        // ---- MFMA for tile it (chain order bit-identical to R4-R10) ----
        f32x4 acc[4];
        #pragma unroll
        for (int n = 0; n < 4; ++n) {
            f32x4 z = {0.f, 0.f, 0.f, 0.f};
            acc[n] = z;
        }
        #pragma unroll
        for (int ks = 0; ks < 4; ++ks) {
            half8 ah, al;
            split8(gc[ks][0], gc[ks][1], ah, al);
            #pragma unroll
            for (int n = 0; n < 4; ++n) {
                const int fo = (ks * 4 + n) * 2048 + lane * 16;
                half8 bh = *reinterpret_cast<const half8*>(smem + fo);
                half8 bl = *reinterpret_cast<const half8*>(smem + fo + 1024);
                acc[n] = __builtin_amdgcn_mfma_f32_16x16x32_f16(ah, bh, acc[n], 0, 0, 0);
                acc[n] = __builtin_amdgcn_mfma_f32_16x16x32_f16(ah, bl, acc[n], 0, 0, 0);
                acc[n] = __builtin_amdgcn_mfma_f32_16x16x32_f16(al, bh, acc[n], 0, 0, 0);
            }
        }

        // ---- epilogue (R4-R10 absmax-0-verified structure) ----
        const int tokb = base + it * 64;
        #pragma unroll
        for (int rg = 0; rg < 4; ++rg) {
            float L0 = acc[0][rg] + b0;
            float L1 = acc[1][rg] + b1;
            float L2 = acc[2][rg] + b2;
            float L3 = acc[3][rg] + b3;

            // exact argmax, lowest-state tie-break: max of (ord(L)<<6 | 63-s)
            unsigned long long k0 = ((unsigned long long)ordf(L0) << 6) | (unsigned)(63 - ( 0 + col));
            unsigned long long k1 = ((unsigned long long)ordf(L1) << 6) | (unsigned)(63 - (16 + col));
            unsigned long long k2 = ((unsigned long long)ordf(L2) << 6) | (unsigned)(63 - (32 + col));
            unsigned long long k3 = ((unsigned long long)ordf(L3) << 6) | (unsigned)(63 - (48 + col));
            unsigned long long ka = k0 > k1 ? k0 : k1;
            unsigned long long kb = k2 > k3 ? k2 : k3;
            unsigned long long kk = ka > kb ? ka : kb;
            #pragma unroll
            for (int d = 1; d <= 8; d <<= 1) {
                unsigned long long o = __shfl_xor(kk, d);
                kk = kk > o ? kk : o;
            }
            const int idx = 63 - (int)(kk & 63ull);

            // softmax scores (no max-subtract: |logit| << 88); feeds loss only
            float e0 = __expf(L0), e1 = __expf(L1), e2 = __expf(L2), e3 = __expf(L3);
            float sm = (e0 + e1) + (e2 + e3);
            #pragma unroll
            for (int d = 1; d <= 8; d <<= 1) sm += __shfl_xor(sm, d);
            const float rinv = __builtin_amdgcn_rcpf(sm);
            sc[0] += e0 * rinv; sc[1] += e1 * rinv;
            sc[2] += e2 * rinv; sc[3] += e3 * rinv;

            cn[0] += (idx ==  0 + col);
            cn[1] += (idx == 16 + col);
            cn[2] += (idx == 32 + col);
            cn[3] += (idx == 48 + col);

            if (col == 0) {
                const int t = tokb + (kg << 2) + rg;
                out[(size_t)t * NHEAD + h] = 1.0f;
                out[(size_t)TH + (size_t)t * NHEAD + h] = (float)idx;
            }
        }
    }

    // wave-level reduction over the 4 kg groups
    #pragma unroll
    for (int n = 0; n < 4; ++n) {
        sc[n] += __shfl_xor(sc[n], 16);
        sc[n] += __shfl_xor(sc[n], 32);
        cn[n] += __shfl_xor(cn[n], 16);
        cn[n] += __shfl_xor(cn[n], 32);
    }

    // block-level reduction (reuse B area; B dead after last MFMA)
    __syncthreads();
    float* redf = (float*)smem;            // [4][64]
    int*   redi = (int*)(smem + 1024);     // [4][64]
    if (kg == 0) {
        #pragma unroll
        for (int n = 0; n < 4; ++n) {
            redf[wave * 64 + n * 16 + col] = sc[n];
            redi[wave * 64 + n * 16 + col] = cn[n];
        }
    }
    __syncthreads();
    if (wave == 0) {
        const float s = redf[lane] + redf[64 + lane] + redf[128 + lane] + redf[192 + lane];
        const int   c = redi[lane] + redi[64 + lane] + redi[128 + lane] + redi[192 + lane];
        atomicAdd(ws_sums + h * NSTATE + lane, s);
        atomicAdd(ws_cnts + h * NSTATE + lane, c);
    }
}

__global__ void router_loss(const float* __restrict__ ws_sums,
                            const int*   __restrict__ ws_cnts,
                            float* __restrict__ out)
{
    const int tid = threadIdx.x;
    float part = 0.0f;
    for (int j = tid; j < NHEAD * NSTATE; j += 256)
        part += (float)ws_cnts[j] * ws_sums[j];

    #pragma unroll
    for (int k = 32; k >= 1; k >>= 1)
        part += __shfl_xor(part, k);

    __shared__ float red[4];
    const int wv = tid >> 6, lane = tid & 63;
    if (lane == 0) red[wv] = part;
    __syncthreads();
    if (tid == 0) {
        const float tot = red[0] + red[1] + red[2] + red[3];
        const float T = (float)TOKENS;
        out[2 * (size_t)TH] = tot * ((float)NSTATE / (T * T));
    }
}

extern "C" void kernel_launch(void* const* d_in, const int* in_sizes, int n_in,
                              void* d_out, int out_size, void* d_ws, size_t ws_size,
                              hipStream_t stream)
{
    const float* x    = (const float*)d_in[0];
    const float* w    = (const float*)d_in[1];
    const float* bias = (const float*)d_in[2];
    float* out = (float*)d_out;

    half8* wfrag   = (half8*)d_ws;
    float* ws_sums = (float*)((char*)d_ws + WFRAG_BYTES);
    int*   ws_cnts = (int*)((char*)d_ws + WFRAG_BYTES + 4096);

    hipMemsetAsync((char*)d_ws + WFRAG_BYTES, 0, 8192, stream);

    prep_w<<<dim3(64), dim3(256), 0, stream>>>(w, wfrag);
    router_mfma<<<dim3(NBLK), dim3(256), 0, stream>>>(x, wfrag, bias, out,
                                                      ws_sums, ws_cnts);
    router_loss<<<dim3(1), dim3(256), 0, stream>>>(ws_sums, ws_cnts, out);
}